// Round 16
// baseline (20.750 us; speedup 1.0000x reference)
//
#include <hip/hip_runtime.h>
#include <math.h>

#define AA 36
#define FWW 106
#define NTOT 122112        /* 32*106*36 */
#define BB 4
#define GG 64
#define STRIDE_PX 16

constexpr int BLOCK = 512;                               // 8 waves
constexpr int NW    = BLOCK / 64;                        // 8
constexpr int BLOCKS_PER_B = (NTOT + BLOCK - 1) / BLOCK; // 239 (last block ragged)
constexpr int NBLK = BB * BLOCKS_PER_B;                  // 956
constexpr int PR_BLOCK = 512;
constexpr int PR_GRID  = (NBLK * 64 + PR_BLOCK - 1) / PR_BLOCK;  // 120

__device__ __forceinline__ float smooth_l1(float x) {
    float ax = fabsf(x);
    return (ax < 1.0f) ? 0.5f * ax * ax : ax - 0.5f;
}
__device__ __forceinline__ float frcp(float x) { return __builtin_amdgcn_rcpf(x); }

#define DPP_ZERO(x, ctrl, rm)                                                 \
    __int_as_float(__builtin_amdgcn_update_dpp(0, __float_as_int(x),          \
                   ctrl, rm, 0xf, true))
#define RLANE_F(v, l) __int_as_float(__builtin_amdgcn_readlane(__float_as_int(v), (l)))

__device__ __forceinline__ float wave_sum64(float x) {   // total in lane 63
    x += DPP_ZERO(x, 0x111, 0xf);
    x += DPP_ZERO(x, 0x112, 0xf);
    x += DPP_ZERO(x, 0x114, 0xf);
    x += DPP_ZERO(x, 0x118, 0xf);
    x += DPP_ZERO(x, 0x142, 0xa);
    x += DPP_ZERO(x, 0x143, 0xc);
    return x;
}

// compute the <=2 single-row x-span windows of virtual block vb
__device__ __forceinline__ void block_windows(int n0,
    float& fxA0, float& fxA1, float& fyA,
    float& fxB0, float& fxB1, float& fyB)
{
    const int nlast = (n0 + BLOCK - 1 < NTOT) ? (n0 + BLOCK - 1) : (NTOT - 1);
    const int s0  = n0 / AA,  s1  = nlast / AA;
    const int sy0 = s0 / FWW, sy1 = s1 / FWW;
    if (sy0 == sy1) {
        fxA0 = (float)((s0 % FWW) * STRIDE_PX); fxA1 = (float)((s1 % FWW) * STRIDE_PX);
        fyA  = (float)(sy0 * STRIDE_PX);
        fxB0 = fxA0; fxB1 = fxA1; fyB = fyA;
    } else {
        fxA0 = (float)((s0 % FWW) * STRIDE_PX); fxA1 = (float)((FWW - 1) * STRIDE_PX);
        fyA  = (float)(sy0 * STRIDE_PX);
        fxB0 = 0.0f;                            fxB1 = (float)((s1 % FWW) * STRIDE_PX);
        fyB  = (float)(sy1 * STRIDE_PX);
    }
}

// ---- pre-pass: one wave per virtual block; lane = GT; exact witness prune ----
__global__ __launch_bounds__(PR_BLOCK) void rpn_prune(
    const float* __restrict__ anchors,
    const float* __restrict__ gt_boxes,
    unsigned long long* __restrict__ masks)
{
    const int gthread = blockIdx.x * PR_BLOCK + threadIdx.x;
    const int vb   = gthread >> 6;        // wave-uniform (64 | wave boundary)
    const int lane = threadIdx.x & 63;
    if (vb >= NBLK) return;               // whole wave exits together

    const int b    = vb / BLOCKS_PER_B;
    const int bpos = vb % BLOCKS_PER_B;
    float fxA0, fxA1, fyA, fxB0, fxB1, fyB;
    block_windows(bpos * BLOCK, fxA0, fxA1, fyA, fxB0, fxB1, fyB);

    const float4 gt = reinterpret_cast<const float4*>(gt_boxes)[b * GG + lane];
    const float gz1p = gt.z + 1.0f;
    const float gw1p = gt.w + 1.0f;
    const float ag   = (gz1p - gt.x) * (gw1p - gt.y);

    bool pass = false;
    for (int a = 0; a < AA; ++a) {         // uniform a -> scalar anchor loads
        const float ax1 = anchors[a * 9 + 0];
        const float ay1 = anchors[a * 9 + 1];
        const float aw  = anchors[a * 9 + 2] - ax1 + 1.0f;
        const float ah  = anchors[a * 9 + 3] - ay1 + 1.0f;
        const float thr = aw * ah + ag;
        float iwA = fminf(fxA1 + ax1 + aw, gz1p) - fmaxf(fxA0 + ax1, gt.x);
        float ihA = fminf(fyA  + ay1 + ah, gw1p) - fmaxf(fyA  + ay1, gt.y);
        iwA = fmaxf(fminf(iwA, aw), 0.0f);
        ihA = fmaxf(fminf(ihA, ah), 0.0f);
        pass |= (3.0f * iwA * ihA >= thr);
        float iwB = fminf(fxB1 + ax1 + aw, gz1p) - fmaxf(fxB0 + ax1, gt.x);
        float ihB = fminf(fyB  + ay1 + ah, gw1p) - fmaxf(fyB  + ay1, gt.y);
        iwB = fmaxf(fminf(iwB, aw), 0.0f);
        ihB = fmaxf(fminf(ihB, ah), 0.0f);
        pass |= (3.0f * iwB * ihB >= thr);
    }
    const unsigned long long m = __ballot(pass);
    if (lane == 0) masks[vb] = m;
}

// ---- main: no prune, no compaction, ONE barrier ----
__global__ __launch_bounds__(BLOCK) void rpn_loss_main(
    const float* __restrict__ cls,
    const float* __restrict__ bbox2d,
    const float* __restrict__ bbox3d,
    const float* __restrict__ anchors,
    const float* __restrict__ means,
    const float* __restrict__ stds,
    const float* __restrict__ gt_boxes,
    const float* __restrict__ gt3d,
    const int*   __restrict__ gt_labels,
    const unsigned long long* __restrict__ masks,
    float4* __restrict__ part)
{
    __shared__ float4 s_red[NW];          // ONLY LDS in the kernel

    const int tid  = threadIdx.x;
    const int lane = tid & 63;
    const int wv   = tid >> 6;
    const int b    = blockIdx.x / BLOCKS_PER_B;            // block-uniform
    const int bpos = blockIdx.x % BLOCKS_PER_B;
    const int n0   = bpos * BLOCK;
    const int n    = n0 + tid;
    const bool valid = (n < NTOT);

    const float4* __restrict__ gtb = reinterpret_cast<const float4*>(gt_boxes) + b * GG;

    // ---- own cls row (issued first; exec-masked for ragged tail) ----
    const size_t row = (size_t)b * NTOT + n;
    float4 c = make_float4(0.f, 0.f, 0.f, 0.f);
    if (valid) c = reinterpret_cast<const float4*>(cls)[row];

    // ---- survivor mask: block-uniform -> one s_load ----
    unsigned long long m = masks[blockIdx.x];

    // ---- this lane's GT (1 KB coalesced, L2-hot) ----
    const float4 gt   = gtb[lane];
    const float  gz1p = gt.z + 1.0f;
    const float  gw1p = gt.w + 1.0f;
    const float  ag   = (gz1p - gt.x) * (gw1p - gt.y);

    // ---- per-thread ROI from global anchors (1.3 KB, L1-hot) ----
    const int aidx  = n % AA;
    const int shift = n / AA;
    const float sx  = (float)((shift % FWW) * STRIDE_PX);
    const float sy  = (float)((shift / FWW) * STRIDE_PX);
    const float a0 = anchors[aidx * 9 + 0];
    const float a1 = anchors[aidx * 9 + 1];
    const float a2 = anchors[aidx * 9 + 2];
    const float a3 = anchors[aidx * 9 + 3];
    const float aw  = a2 - a0 + 1.0f;
    const float ah  = a3 - a1 + 1.0f;
    const float x1  = sx + a0;
    const float y1  = sy + a1;
    const float x2p = x1 + aw;
    const float y2p = y1 + ah;
    const float ar  = aw * ah;

    // ---- CE logsumexp (GT-independent; overlaps gt/mask latency) ----
    const float lse = __logf(__expf(c.x) + __expf(c.y) + __expf(c.z) + __expf(c.w));

    // ---- argmax over survivors: ctz walk + readlane broadcasts (first-max) ----
    float bi = 0.0f, bS = 1.0f;
    int   bk = 0;
    while (m) {
        const int g = (int)__builtin_ctzll(m);   // wave-uniform (mask uniform)
        m &= (m - 1ull);
        const float gxs = RLANE_F(gt.x, g);
        const float gys = RLANE_F(gt.y, g);
        const float gzs = RLANE_F(gz1p, g);
        const float gws = RLANE_F(gw1p, g);
        const float ags = RLANE_F(ag,   g);
        const float iw = fminf(x2p, gzs) - fmaxf(x1, gxs);
        const float ih = fmaxf(fminf(y2p, gws) - fmaxf(y1, gys), 0.0f);
        const float inter = iw * ih;              // <=0 can never win (bi>=0)
        const float S     = ar + ags;
        const bool upd = inter * bS > bi * S;     // exact cross-mult, first-max
        bi = upd ? inter : bi;
        bS = upd ? S     : bS;
        bk = upd ? g     : bk;
    }
    const bool fg = valid && (3.0f * bi >= bS);   // exact: best_iou >= 0.5
    // pruned GTs provably have iou < 0.5 for every ROI in this block

    int label = 0;
    if (fg) label = gt_labels[b * GG + bk];
    const float csel = (label == 0) ? c.x : (label == 1) ? c.y :
                       (label == 2) ? c.z : c.w;
    const float ce = valid ? (lse - csel) : 0.0f;

    // ---- bbox losses (fg only; rare, exec-masked) ----
    float l23 = 0.0f;
    if (fg) {
        const float cx  = x1 + 0.5f * aw;
        const float cy  = y1 + 0.5f * ah;
        const float rw  = frcp(aw);
        const float rh  = frcp(ah);
        const float4 gq = gtb[bk];                // divergent, rare, L2-hot
        const float gw_ = gq.z - gq.x + 1.0f;
        const float gh_ = gq.w - gq.y + 1.0f;
        const float gcx = gq.x + 0.5f * gw_;
        const float gcy = gq.y + 0.5f * gh_;
        float t2[4];
        t2[0] = (gcx - cx) * rw;
        t2[1] = (gcy - cy) * rh;
        t2[2] = __logf(gw_ * rw);
        t2[3] = __logf(gh_ * rh);
        const float4 p2 = reinterpret_cast<const float4*>(bbox2d)[row];
        const float p2a[4] = {p2.x, p2.y, p2.z, p2.w};
        #pragma unroll
        for (int k = 0; k < 4; ++k)
            l23 += smooth_l1(p2a[k] - (t2[k] - means[k]) * frcp(stds[k]));

        const float an4 = anchors[aidx * 9 + 4];
        const float an5 = anchors[aidx * 9 + 5];
        const float an6 = anchors[aidx * 9 + 6];
        const float an7 = anchors[aidx * 9 + 7];
        const float an8 = anchors[aidx * 9 + 8];
        const float* g3 = gt3d + ((size_t)b * GG + bk) * 7;
        float t3[7];
        t3[0] = (g3[0] - cx) * rw;
        t3[1] = (g3[1] - cy) * rh;
        t3[2] = g3[2] - an4;
        t3[3] = __logf(g3[3] * frcp(an5));
        t3[4] = __logf(g3[4] * frcp(an6));
        t3[5] = __logf(g3[5] * frcp(an7));
        t3[6] = g3[6] - an8;
        const float* p3 = bbox3d + row * 7;
        #pragma unroll
        for (int k = 0; k < 7; ++k)
            l23 += smooth_l1(p3[k] - (t3[k] - means[4 + k]) * frcp(stds[4 + k]));
    }

    // ---- reduction: DPP wave sums, nfg via ballot; the ONLY barrier ----
    const float vce = wave_sum64(ce);
    const float vl  = wave_sum64(l23);
    const float nfgw = (float)__popcll(__ballot(fg));
    if (lane == 63) s_red[wv] = make_float4(vce, vl, nfgw, 0.f);
    __syncthreads();
    if (tid < NW) {
        float4 p = s_red[tid];
        #pragma unroll
        for (int mm = 1; mm < NW; mm <<= 1) {
            p.x += __shfl_xor(p.x, mm, 64);
            p.y += __shfl_xor(p.y, mm, 64);
            p.z += __shfl_xor(p.z, mm, 64);
        }
        if (tid == 0) part[blockIdx.x] = p;
    }
}

__global__ __launch_bounds__(256) void rpn_loss_fin(
    const float4* __restrict__ part, float* __restrict__ out)
{
    __shared__ float4 sh[4];
    float ce = 0.f, l23 = 0.f, nfg = 0.f;
    for (int i = threadIdx.x; i < NBLK; i += 256) {
        const float4 p = part[i];
        ce += p.x; l23 += p.y; nfg += p.z;
    }
    ce  = wave_sum64(ce);
    l23 = wave_sum64(l23);
    nfg = wave_sum64(nfg);
    const int lane = threadIdx.x & 63;
    const int wv   = threadIdx.x >> 6;
    if (lane == 63) sh[wv] = make_float4(ce, l23, nfg, 0.f);
    __syncthreads();
    if (threadIdx.x == 0) {
        float a = 0.f, l = 0.f, g = 0.f;
        #pragma unroll
        for (int i = 0; i < 4; ++i) { a += sh[i].x; l += sh[i].y; g += sh[i].z; }
        out[0] = a / (float)((size_t)BB * NTOT) + l / fmaxf(g, 1.0f);
    }
}

extern "C" void kernel_launch(void* const* d_in, const int* in_sizes, int n_in,
                              void* d_out, int out_size, void* d_ws, size_t ws_size,
                              hipStream_t stream) {
    const float* cls     = (const float*)d_in[0];
    // d_in[1] = prob (unused by the loss)
    const float* bbox2d  = (const float*)d_in[2];
    const float* bbox3d  = (const float*)d_in[3];
    // d_in[4] = rois — reconstructed from anchors + linear index
    const float* anchors = (const float*)d_in[5];
    const float* means   = (const float*)d_in[6];
    const float* stds    = (const float*)d_in[7];
    const float* gtb     = (const float*)d_in[8];
    const float* gt3     = (const float*)d_in[9];
    const int*   glbl    = (const int*)d_in[10];

    float4* part = (float4*)d_ws;                             // NBLK partials
    unsigned long long* masks = (unsigned long long*)(part + NBLK);  // NBLK masks
    float*  out  = (float*)d_out;

    rpn_prune<<<dim3(PR_GRID), PR_BLOCK, 0, stream>>>(anchors, gtb, masks);
    rpn_loss_main<<<dim3(NBLK), BLOCK, 0, stream>>>(cls, bbox2d, bbox3d, anchors,
                                                    means, stds, gtb, gt3, glbl,
                                                    masks, part);
    rpn_loss_fin<<<1, 256, 0, stream>>>(part, out);
}